// Round 10
// baseline (89.072 us; speedup 1.0000x reference)
//
#include <hip/hip_runtime.h>

// Problem constants: x(64,32768,6) f32, templates(16,6,80), delays(16,6)
#define BB 64
#define SS 32768
#define FF 6
#define EE 16
#define LL 80
#define KK 480      // F*L, K order: k = 6*r + f  (feature-minor!)
#define NSL 15      // K/32
#define TBLK 256    // time positions per block (4 waves x 64)
#define SPLIT 9     // s < SPLIT from LDS, s >= SPLIT direct from global
#define NGF (NSL - SPLIT)
#define SLAB 2048   // f16 elems per wave slab (covers 1992 needed)
#define X16OFF 32768

typedef _Float16 half8 __attribute__((ext_vector_type(8)));
typedef float f32x4 __attribute__((ext_vector_type(4)));
typedef float f32x4u __attribute__((ext_vector_type(4), aligned(4)));
typedef __fp16 h2 __attribute__((ext_vector_type(2)));

__device__ __forceinline__ half8 as_h8(f32x4 v) {
    union { f32x4 f; half8 h; } u; u.f = v; return u.h;
}
__device__ __forceinline__ half8 ldg_h8u(const _Float16* p) {   // 4B-aligned global 16B load
    union { f32x4 f; half8 h; } u; u.f = (f32x4)(*(const f32x4u*)p); return u.h;
}

// ---- prep: wrev2 (k=6r+f order) + x16 (flat f16 copy of x) ----
__global__ __launch_bounds__(256) void prep_all(const float* __restrict__ x,
                                                const float* __restrict__ tpl,
                                                const float* __restrict__ dly,
                                                _Float16* __restrict__ wrev2,
                                                _Float16* __restrict__ x16) {
    int tid = threadIdx.x;
    if (blockIdx.x < 30) {
        int n = blockIdx.x * 256 + tid;
        if (n < EE * KK) {
            int e = n / KK, k = n - e * KK;
            int r = k / FF, f = k - r * FF;
            float dl = fminf(fmaxf(dly[e * FF + f], -10.f), 10.f);
            int d = (int)rintf(dl);                    // RNE, matches jnp.round
            int src = LL - 1 - r - d;                  // flip + delay
            float v = (src >= 0 && src < LL) ? tpl[(e * FF + f) * LL + src] : 0.f;
            wrev2[n] = (_Float16)v;                    // NOT pre-scaled (f16 denormals)
        }
    }
    // f16 copy: one thread per time position (6 values)
    size_t i = (size_t)blockIdx.x * 256 + tid;         // < 64*32768 exactly
    const float* xp = x + i * 6;
    float2 a = *(const float2*)(xp + 0);
    float2 bq = *(const float2*)(xp + 2);
    float2 c = *(const float2*)(xp + 4);
    unsigned u0, u1, u2;
    { h2 h = __builtin_amdgcn_cvt_pkrtz(a.x, a.y);  u0 = *(unsigned*)&h; }
    { h2 h = __builtin_amdgcn_cvt_pkrtz(bq.x, bq.y); u1 = *(unsigned*)&h; }
    { h2 h = __builtin_amdgcn_cvt_pkrtz(c.x, c.y);  u2 = *(unsigned*)&h; }
    unsigned* dst = (unsigned*)x16 + i * 3;
    dst[0] = u0; dst[1] = u1; dst[2] = u2;
}

// ---- main: barrier-free, wave-independent; DMA slab + hybrid LDS/global fragments ----
__global__ __launch_bounds__(256, 3) void corr_new(const _Float16* __restrict__ x16,
                                                   const _Float16* __restrict__ wrev2,
                                                   float* __restrict__ out) {
    __shared__ alignas(16) _Float16 xs[4][SLAB];       // 16,384 B (one slab per wave)

    int tid = threadIdx.x, lane = tid & 63, w = tid >> 6;
    int e = lane & 15, g = lane >> 4;
    int b = blockIdx.x >> 7;
    int t0 = (blockIdx.x & 127) << 8;

    // B fragments (templates) into registers, pinned (compiler parks in AGPRs)
    f32x4 bqv[NSL];
    #pragma unroll
    for (int s = 0; s < NSL; s++)
        bqv[s] = *(const f32x4*)&wrev2[e * KK + 32 * s + 8 * g];   // 16B-aligned
    #pragma unroll
    for (int s = 0; s < NSL; s++)
        asm volatile("" : "+v"(bqv[s]));

    // wave-private window base: pos = t0 + w - 39  (flat f16 index = pos*6)
    const _Float16* xw = x16 + ((long)b * SS + t0 + w - 39) * 6;

    // stage own slab: 4 x global_load_lds dwordx4 (lane l -> LDS 16B chunk l)
    #pragma unroll
    for (int c = 0; c < 4; c++)
        __builtin_amdgcn_global_load_lds(
            (const __attribute__((address_space(1))) void*)(xw + 512 * c + 8 * lane),
            (__attribute__((address_space(3))) void*)&xs[w][512 * c], 16, 0, 0);
    asm volatile("s_waitcnt vmcnt(0)" ::: "memory");
    __builtin_amdgcn_sched_barrier(0);

    // edge fixups (rare, wave-uniform): zero out-of-range positions
    if (t0 == 0) {
        int lim = (39 - w) * 6;
        for (int j = lane; j < lim; j += 64) xs[w][j] = (_Float16)0.f;
    }
    bool gsplit = (t0 + TBLK < SS);
    if (!gsplit) {
        int lo = (SS - t0 - w + 39) * 6;
        for (int j = lo + lane; j < SLAB; j += 64) xs[w][j] = (_Float16)0.f;
    }

    const _Float16* xls = &xs[w][0];
    #pragma unroll
    for (int tt = 0; tt < 4; tt++) {
        int R = tt * 16 + e;               // A-row (t-stride 4 within phase w)
        int base = 24 * R + 8 * g;         // elem offset: byte 48R+16g (16B-aligned)
        f32x4 acc = {0.f, 0.f, 0.f, 0.f};

        half8 gf[NGF];
        if (gsplit) {
            #pragma unroll
            for (int s2 = 0; s2 < NGF; s2++)
                gf[s2] = ldg_h8u(xw + base + 32 * (SPLIT + s2));      // L1/L2-hit
        }
        #pragma unroll
        for (int s = 0; s < SPLIT; s++) {
            half8 av = *(const half8*)&xls[base + 32 * s];            // ds_read_b128
            acc = __builtin_amdgcn_mfma_f32_16x16x32_f16(av, as_h8(bqv[s]), acc, 0, 0, 0);
        }
        if (gsplit) {
            #pragma unroll
            for (int s2 = 0; s2 < NGF; s2++)
                acc = __builtin_amdgcn_mfma_f32_16x16x32_f16(gf[s2], as_h8(bqv[SPLIT + s2]), acc, 0, 0, 0);
        } else {
            #pragma unroll
            for (int s = SPLIT; s < NSL; s++) {
                half8 av = *(const half8*)&xls[base + 32 * s];
                acc = __builtin_amdgcn_mfma_f32_16x16x32_f16(av, as_h8(bqv[s]), acc, 0, 0, 0);
            }
        }
        // D: row = g*4+j, col = e ; t = t0 + w + 4*(tt*16 + row)
        #pragma unroll
        for (int j = 0; j < 4; j++) {
            int row = tt * 16 + g * 4 + j;
            int t = t0 + w + 4 * row;
            float v = acc[j] * (1.0f / 480.0f);
            if (t == SS - 1) v = 0.f;      // reference zero-pads the last position
            out[((size_t)b * SS + t) * EE + e] = v;
        }
    }
}

// ======== fallback path (ws too small): round-8 kernels, verbatim ========
#define WROW 336
#define UPP 166
#define NUNITS 664

__global__ void prep_old(const float* __restrict__ tpl, const float* __restrict__ dly,
                         _Float16* __restrict__ wrev) {
    int n = blockIdx.x * 256 + threadIdx.x;
    if (n >= EE * KK) return;
    int e = n / KK, k = n - e * KK;
    int f = k / LL, r = k - f * LL;
    int m = LL - 1 - r;
    float dl = fminf(fmaxf(dly[e * FF + f], -10.f), 10.f);
    int d = (int)rintf(dl);
    int src = m - d;
    float v = (src >= 0 && src < LL) ? tpl[(e * FF + f) * LL + src] : 0.f;
    wrev[n] = (_Float16)v;
}

__global__ __launch_bounds__(128, 4) void corr_old(const float* __restrict__ x,
                                                   const _Float16* __restrict__ wrev,
                                                   float* __restrict__ out) {
    __shared__ alignas(16) _Float16 xs[4][FF][WROW];
    int tid = threadIdx.x, lane = tid & 63, w = tid >> 6;
    int e = lane & 15, g = lane >> 4;
    int b = blockIdx.x >> 7, t0 = (blockIdx.x & 127) << 8;
    const float* xb = x + (size_t)b * (SS * FF);
    f32x4 bqv[NSL];
    #pragma unroll
    for (int s = 0; s < NSL; s++)
        bqv[s] = *(const f32x4*)&wrev[e * KK + 32 * s + 8 * g];
    #pragma unroll
    for (int s = 0; s < NSL; s++)
        asm volatile("" : "+v"(bqv[s]));
    bool edge = (t0 - 39 < 0) | (t0 + 296 > SS);
    for (int u = tid; u < NUNITS; u += 128) {
        int phi = u / UPP;
        int i2 = (u - phi * UPP) * 2;
        int pos = t0 + phi - 39 + i2;
        float va[12];
        if (!edge) {
            const float* xp = xb + (size_t)pos * FF;
            #pragma unroll
            for (int q = 0; q < 6; q++) *(float2*)&va[2 * q] = *(const float2*)&xp[2 * q];
        } else {
            #pragma unroll
            for (int q = 0; q < 2; q++) {
                int p = pos + q;
                bool ok = (p >= 0) && (p < SS);
                #pragma unroll
                for (int f = 0; f < FF; f++) va[q * 6 + f] = ok ? xb[(size_t)p * FF + f] : 0.f;
            }
        }
        #pragma unroll
        for (int f = 0; f < FF; f++) {
            h2 hp = __builtin_amdgcn_cvt_pkrtz(va[f], va[6 + f]);
            *(h2*)&xs[phi][f][i2] = hp;
        }
    }
    __syncthreads();
    #pragma unroll
    for (int phi = 0; phi < 4; phi++) {
        const char* xph = (const char*)&xs[phi][0][0];
        #pragma unroll
        for (int tt = 0; tt < 2; tt++) {
            int R = 32 * w + 16 * tt + e;
            f32x4 acc = {0.f, 0.f, 0.f, 0.f};
            #pragma unroll
            for (int s = 0; s < NSL; s++) {
                int k0 = 32 * s + 8 * g;
                int f = (k0 * 205) >> 14;
                int r0 = k0 - 80 * f;
                const char* p = xph + 2 * (f * WROW + 4 * R + r0);
                uint2 lo = *(const uint2*)p;
                uint2 hi = *(const uint2*)(p + 8);
                union { unsigned u[4]; half8 h; } av;
                av.u[0] = lo.x; av.u[1] = lo.y; av.u[2] = hi.x; av.u[3] = hi.y;
                acc = __builtin_amdgcn_mfma_f32_16x16x32_f16(av.h, as_h8(bqv[s]), acc, 0, 0, 0);
            }
            #pragma unroll
            for (int j = 0; j < 4; j++) {
                int row = 32 * w + 16 * tt + g * 4 + j;
                int t = t0 + phi + 4 * row;
                float v = acc[j] * (1.0f / 480.0f);
                if (t == SS - 1) v = 0.f;
                out[((size_t)b * SS + t) * EE + e] = v;
            }
        }
    }
}

extern "C" void kernel_launch(void* const* d_in, const int* in_sizes, int n_in,
                              void* d_out, int out_size, void* d_ws, size_t ws_size,
                              hipStream_t stream) {
    const float* x = (const float*)d_in[0];
    const float* tpl = (const float*)d_in[1];
    const float* dly = (const float*)d_in[2];
    float* out = (float*)d_out;

    size_t need = (size_t)X16OFF + (size_t)BB * SS * FF * 2 + 4096;
    if (ws_size >= need) {
        _Float16* wrev2 = (_Float16*)d_ws;
        _Float16* x16 = (_Float16*)((char*)d_ws + X16OFF);
        prep_all<<<BB * SS / 256, 256, 0, stream>>>(x, tpl, dly, wrev2, x16);
        corr_new<<<BB * (SS / TBLK), 256, 0, stream>>>(x16, wrev2, out);
    } else if (ws_size >= (size_t)(EE * KK * sizeof(_Float16))) {
        _Float16* wrev = (_Float16*)d_ws;
        prep_old<<<(EE * KK + 255) / 256, 256, 0, stream>>>(tpl, dly, wrev);
        corr_old<<<BB * (SS / TBLK), 128, 0, stream>>>(x, wrev, out);
    }
}